// Round 4
// baseline (422.680 us; speedup 1.0000x reference)
//
#include <hip/hip_runtime.h>

// SelfAttention: B=8, S=2048, D=1024, U=1024, fp32 in/out.
// R8: revert to the R4 skeleton (2-phase, single-buffered 32KB LDS, 128^2
// tile, __syncthreads pair per K-tile — the ~3-4 blocks/CU cross-block
// overlap mechanism that measured 45% MfmaUtil), but fix its LDS:MFMA
// imbalance: R4's 4 waves x (64x64) did 64 ds_read_b128 per 128 MFMA
// (ratio 1.24, B-frags read 2x). R8 uses 2-wave (128-thread) blocks, each
// wave owning 64x128: 24 reads per 64 MFMA (ratio 0.93, no B duplication
// across n). Same grids, same staging swizzle (slot (row,c8) holds global
// colgroup c8^(row&7), verified conflict-free), same epilogue math with
// wn removed (j spans 8 column-fragments).
// Occupancy: VGPR ~100 + 128 acc (AGPR) < 256/wave -> 2 waves/SIMD;
// LDS 32KB -> 4 blocks/CU co-resident.
// R5-R7 post-mortem: 256^2 1-block/CU phase schedules (barriered or not)
// all lost to cross-block free-running overlap; that line is abandoned.
// Workspace: 33.6(Xh) + 6.3(WbT) + 33.6*3(QKV) + 67.1(P) = 207.7 MB

#define BM 128
#define BN 128
#define BK 64

typedef _Float16 half8  __attribute__((ext_vector_type(8)));
typedef _Float16 half4v __attribute__((ext_vector_type(4)));
typedef _Float16 half2v __attribute__((ext_vector_type(2)));
typedef float    floatx4 __attribute__((ext_vector_type(4)));

// ---- async stage: 128x64 fp16 tile (row-major, ld elems) -> LDS, swizzled ----
// 128 threads x 8 chunks x 16B = 16 KB.
__device__ __forceinline__ void stage_async(const _Float16* __restrict__ src, int ld,
                                            _Float16* __restrict__ dst, int wave, int lane) {
#pragma unroll
    for (int i = 0; i < 8; ++i) {
        int chunk = wave * 8 + i;
        int L = chunk * 64 + lane;
        int row = L >> 3, c8 = L & 7;
        int cg = c8 ^ (row & 7);
        __builtin_amdgcn_global_load_lds(
            (const __attribute__((address_space(1))) unsigned int*)(src + (size_t)row * ld + cg * 8),
            (__attribute__((address_space(3))) unsigned int*)(dst + chunk * 512),
            16, 0, 0);
    }
}

// ---- one BK=64 K-step: per-wave 64x128 sub-tile (4 a-frags x 8 b-frags) ----
__device__ __forceinline__ void mfma_accum(const _Float16* __restrict__ As,
                                           const _Float16* __restrict__ Bs,
                                           int wm, int l15, int q4,
                                           floatx4 acc[4][8]) {
#pragma unroll
    for (int kk = 0; kk < 2; ++kk) {
        half8 a[4], b[8];
#pragma unroll
        for (int i = 0; i < 4; ++i) {
            int row = wm * 64 + i * 16 + l15;
            int cg = (kk * 4 + q4) ^ (row & 7);
            a[i] = *(const half8*)(As + row * 64 + cg * 8);
        }
#pragma unroll
        for (int j = 0; j < 8; ++j) {
            int row = j * 16 + l15;
            int cg = (kk * 4 + q4) ^ (row & 7);
            b[j] = *(const half8*)(Bs + row * 64 + cg * 8);
        }
#pragma unroll
        for (int i = 0; i < 4; ++i)
#pragma unroll
            for (int j = 0; j < 8; ++j)
                acc[i][j] = __builtin_amdgcn_mfma_f32_16x16x32_f16(a[i], b[j], acc[i][j], 0, 0, 0);
    }
}

// pk-add sum of 8 halves -> float
__device__ __forceinline__ float sum8h(half8 a) {
    union { half8 v; half2v h2[4]; } u; u.v = a;
    half2v s0 = u.h2[0] + u.h2[1];
    half2v s1 = u.h2[2] + u.h2[3];
    half2v s  = s0 + s1;
    return (float)s[0] + (float)s[1];
}

// ---- kernel 0: cast X fp32 -> fp16 ----
__global__ void cast_x(const float* __restrict__ X, _Float16* __restrict__ Xh) {
    size_t i = ((size_t)blockIdx.x * 256 + threadIdx.x) * 8;
    float4 v0 = *(const float4*)(X + i);
    float4 v1 = *(const float4*)(X + i + 4);
    half8 hh;
    hh[0] = (_Float16)v0.x; hh[1] = (_Float16)v0.y; hh[2] = (_Float16)v0.z; hh[3] = (_Float16)v0.w;
    hh[4] = (_Float16)v1.x; hh[5] = (_Float16)v1.y; hh[6] = (_Float16)v1.z; hh[7] = (_Float16)v1.w;
    *(half8*)(Xh + i) = hh;
}

// ---- kernel 1: transpose-cast weights to fp16 ----
__global__ void prep_weights(const float* __restrict__ Wq, const float* __restrict__ Wk,
                             const float* __restrict__ Wv, _Float16* __restrict__ WbT) {
    int g = blockIdx.z;
    const float* W = (g == 0) ? Wq : (g == 1) ? Wk : Wv;
    __shared__ float tile[32][33];
    int u0 = blockIdx.x * 32, d0 = blockIdx.y * 32;
    int tx = threadIdx.x & 31, ty = threadIdx.x >> 5;
#pragma unroll
    for (int i = 0; i < 32; i += 8)
        tile[ty + i][tx] = W[(size_t)(d0 + ty + i) * 1024 + (u0 + tx)];
    __syncthreads();
#pragma unroll
    for (int i = 0; i < 32; i += 8)
        WbT[(size_t)g * 1024 * 1024 + (size_t)(u0 + ty + i) * 1024 + (d0 + tx)] =
            (_Float16)tile[tx][ty + i];
}

// ---- kernel 2: fused QKV projection ----
// grid (24,128): blockIdx.x>>3 selects Q/K/V (block-uniform), &7 is the u-tile.
__global__ __launch_bounds__(128, 2)
void qkv_gemm(const _Float16* __restrict__ Xh, const _Float16* __restrict__ WbT,
              _Float16* __restrict__ Qh, _Float16* __restrict__ Kh,
              _Float16* __restrict__ Vt) {
    __shared__ __align__(16) _Float16 As[BM * BK];
    __shared__ __align__(16) _Float16 Bs[BN * BK];
    int t = threadIdx.x;
    int lane = t & 63, wave = t >> 6;
    int wm = wave;
    int l15 = lane & 15, q4 = lane >> 4;
    int m0 = blockIdx.y * BM, n0 = blockIdx.x * BN;
    floatx4 acc[4][8] = {};
    for (int kt = 0; kt < 1024; kt += BK) {
        __syncthreads();
        stage_async(Xh + (size_t)m0 * 1024 + kt, 1024, As, wave, lane);
        stage_async(WbT + (size_t)n0 * 1024 + kt, 1024, Bs, wave, lane);
        __syncthreads();
        mfma_accum(As, Bs, wm, l15, q4, acc);
    }
    // block-uniform routing: which matrix, which batch
    int which = blockIdx.x >> 3;            // 0=Q 1=K 2=V
    int u0 = (blockIdx.x & 7) * BN;         // column offset within 1024
    int b = m0 >> 11;                       // batch (128-row tiles never straddle)
    int sbase = (m0 & 2047) + wm * 64;      // sequence offset of this wave's rows
    if (which < 2) {
        _Float16* dst = which ? Kh : Qh;
        _Float16* db = dst + (size_t)b * 2048 * 1024;
#pragma unroll
        for (int i = 0; i < 4; ++i)
#pragma unroll
            for (int j = 0; j < 8; ++j)
#pragma unroll
                for (int r = 0; r < 4; ++r) {
                    int s = sbase + i * 16 + q4 * 4 + r;
                    int u = u0 + j * 16 + l15;
                    db[(size_t)s * 1024 + u] = (_Float16)acc[i][j][r];
                }
    } else {
        _Float16* vb = Vt + (size_t)b * 1024 * 2048;
#pragma unroll
        for (int i = 0; i < 4; ++i)
#pragma unroll
            for (int j = 0; j < 8; ++j) {
                int s = sbase + i * 16 + q4 * 4;          // 4 consecutive s (r=0..3)
                int u = u0 + j * 16 + l15;
                half4v pk;
#pragma unroll
                for (int r = 0; r < 4; ++r) pk[r] = (_Float16)acc[i][j][r];
                *(half4v*)(vb + (size_t)u * 2048 + s) = pk;  // 8B aligned (s%4==0)
            }
    }
}

// ---- kernel 3: scores, epilogue = exp + store only ----
__global__ __launch_bounds__(128, 2)
void scores_gemm(const _Float16* __restrict__ Qh, const _Float16* __restrict__ Kh,
                 _Float16* __restrict__ P) {
    __shared__ __align__(16) _Float16 As[BM * BK];
    __shared__ __align__(16) _Float16 Bs[BN * BK];
    int t = threadIdx.x;
    int lane = t & 63, wave = t >> 6;
    int wm = wave;
    int l15 = lane & 15, q4 = lane >> 4;
    int m0 = blockIdx.y * BM, n0 = blockIdx.x * BN;
    int batch = blockIdx.z;
    const _Float16* A = Qh + (size_t)batch * 2048 * 1024;
    const _Float16* B = Kh + (size_t)batch * 2048 * 1024;
    floatx4 acc[4][8] = {};
    for (int kt = 0; kt < 1024; kt += BK) {
        __syncthreads();
        stage_async(A + (size_t)m0 * 1024 + kt, 1024, As, wave, lane);
        stage_async(B + (size_t)n0 * 1024 + kt, 1024, Bs, wave, lane);
        __syncthreads();
        mfma_accum(As, Bs, wm, l15, q4, acc);
    }
    _Float16* Pb = P + (size_t)batch * 2048 * 2048;
#pragma unroll
    for (int i = 0; i < 4; ++i)
#pragma unroll
        for (int j = 0; j < 8; ++j)
#pragma unroll
            for (int r = 0; r < 4; ++r) {
                int m = m0 + wm * 64 + i * 16 + q4 * 4 + r;
                int n = n0 + j * 16 + l15;
                Pb[(size_t)m * 2048 + n] = (_Float16)__expf(acc[i][j][r] * 0.03125f);
            }
}

// ---- kernel 4: P @ V with inline rowsum + normalization ----
__global__ __launch_bounds__(128, 2)
void pv_gemm(const _Float16* __restrict__ P, const _Float16* __restrict__ Vt,
             float* __restrict__ out) {
    __shared__ __align__(16) _Float16 As[BM * BK];
    __shared__ __align__(16) _Float16 Bs[BN * BK];
    int t = threadIdx.x;
    int lane = t & 63, wave = t >> 6;
    int wm = wave;
    int l15 = lane & 15, q4 = lane >> 4;
    int m0 = blockIdx.y * BM, n0 = blockIdx.x * BN;
    int batch = blockIdx.z;
    const _Float16* A = P + (size_t)batch * 2048 * 2048;
    const _Float16* B = Vt + (size_t)batch * 1024 * 2048;
    floatx4 acc[4][8] = {};
    float rsum[4] = {0.f, 0.f, 0.f, 0.f};  // partial rowsum of row i*16+l15, this lane's k-slices
    for (int kt = 0; kt < 2048; kt += BK) {
        __syncthreads();
        stage_async(A + (size_t)m0 * 2048 + kt, 2048, As, wave, lane);
        stage_async(B + (size_t)n0 * 2048 + kt, 2048, Bs, wave, lane);
        __syncthreads();
#pragma unroll
        for (int kk = 0; kk < 2; ++kk) {
            half8 a[4], b[8];
#pragma unroll
            for (int i = 0; i < 4; ++i) {
                int row = wm * 64 + i * 16 + l15;
                int cg = (kk * 4 + q4) ^ (row & 7);
                a[i] = *(const half8*)(As + row * 64 + cg * 8);
                rsum[i] += sum8h(a[i]);
            }
#pragma unroll
            for (int j = 0; j < 8; ++j) {
                int row = j * 16 + l15;
                int cg = (kk * 4 + q4) ^ (row & 7);
                b[j] = *(const half8*)(Bs + row * 64 + cg * 8);
            }
#pragma unroll
            for (int i = 0; i < 4; ++i)
#pragma unroll
                for (int j = 0; j < 8; ++j)
                    acc[i][j] = __builtin_amdgcn_mfma_f32_16x16x32_f16(a[i], b[j], acc[i][j], 0, 0, 0);
        }
    }
    // merge the 4 q4 k-slices: lanes sharing l15 hold partials of the same row
    float rsumf[4];
#pragma unroll
    for (int i = 0; i < 4; ++i) {
        float v = rsum[i] + __shfl_xor(rsum[i], 16);
        rsumf[i] = v + __shfl_xor(v, 32);   // full rowsum of row i*16+l15, all lanes
    }
    float* ob = out + (size_t)batch * 2048 * 1024;
#pragma unroll
    for (int i = 0; i < 4; ++i)
#pragma unroll
        for (int r = 0; r < 4; ++r) {
            int rloc = q4 * 4 + r;                       // C/D row within 16x16
            float inv = 1.0f / __shfl(rsumf[i], rloc);   // lane rloc holds row rloc's sum
            int m = m0 + wm * 64 + i * 16 + rloc;
#pragma unroll
            for (int j = 0; j < 8; ++j) {
                int n = n0 + j * 16 + l15;
                ob[(size_t)m * 1024 + n] = acc[i][j][r] * inv;
            }
        }
}

extern "C" void kernel_launch(void* const* d_in, const int* in_sizes, int n_in,
                              void* d_out, int out_size, void* d_ws, size_t ws_size,
                              hipStream_t stream) {
    const float* X  = (const float*)d_in[0];
    const float* Wq = (const float*)d_in[1];
    const float* Wk = (const float*)d_in[2];
    const float* Wv = (const float*)d_in[3];
    float* out = (float*)d_out;

    char* ws = (char*)d_ws;
    size_t off = 0;
    _Float16* Xh  = (_Float16*)(ws + off); off += (size_t)8 * 2048 * 1024 * 2;
    _Float16* WbT = (_Float16*)(ws + off); off += (size_t)3 * 1024 * 1024 * 2;
    _Float16* Qh  = (_Float16*)(ws + off); off += (size_t)8 * 2048 * 1024 * 2;
    _Float16* Kh  = (_Float16*)(ws + off); off += (size_t)8 * 2048 * 1024 * 2;
    _Float16* Vt  = (_Float16*)(ws + off); off += (size_t)8 * 1024 * 2048 * 2;
    _Float16* P   = (_Float16*)(ws + off); off += (size_t)8 * 2048 * 2048 * 2;

    cast_x      <<<dim3(8192, 1, 1), 256, 0, stream>>>(X, Xh);
    prep_weights<<<dim3(32, 32, 3), 256, 0, stream>>>(Wq, Wk, Wv, WbT);
    qkv_gemm    <<<dim3(24, 128, 1), 128, 0, stream>>>(Xh, WbT, Qh, Kh, Vt);
    scores_gemm <<<dim3(16, 16, 8), 128, 0, stream>>>(Qh, Kh, P);
    pv_gemm     <<<dim3(8, 16, 8),  128, 0, stream>>>(P, Vt, out);
}

// Round 5
// 399.415 us; speedup vs baseline: 1.0582x; 1.0582x over previous
//
#include <hip/hip_runtime.h>

// SelfAttention: B=8, S=2048, D=1024, U=1024, fp32 in/out.
// R9: per-kernel best-of-measured combine.
//  - qkv_gemm: R4 structure (128^2 tile, 256 threads / 4 waves, 2-phase
//    __syncthreads loop, 32KB LDS -> ~3 blocks/CU cross-block overlap;
//    measured 107us, MfmaUtil 45%).
//  - scores/pv: R6 structure (256^2 tile, 512 threads / 8 waves, 4 uniform
//    phases per K-tile, counted vmcnt, 128KB LDS; R6's remainder beat R4's
//    by ~38us on these kernels).
// Round ledger: R5/R6/R7 256^2 schedules and R8 fat-wave all lost to R4 on
// qkv (barrier lockstep or occupancy loss); R6 won on scores/pv. Combining
// measured winners instead of inventing a 5th schedule.
// Staging swizzle everywhere: LDS slot (row,c8) holds global colgroup
// c8^(row&7) -> verified conflict-free (SQ_LDS_BANK_CONFLICT=0 all rounds).
// Workspace: 33.6(Xh) + 6.3(WbT) + 33.6*3(QKV) + 67.1(P) = 207.7 MB

typedef _Float16 half8  __attribute__((ext_vector_type(8)));
typedef _Float16 half4v __attribute__((ext_vector_type(4)));
typedef _Float16 half2v __attribute__((ext_vector_type(2)));
typedef float    floatx4 __attribute__((ext_vector_type(4)));

// ============================ shared helpers ============================

// pk-add sum of 8 halves -> float
__device__ __forceinline__ float sum8h(half8 a) {
    union { half8 v; half2v h2[4]; } u; u.v = a;
    half2v s0 = u.h2[0] + u.h2[1];
    half2v s1 = u.h2[2] + u.h2[3];
    half2v s  = s0 + s1;
    return (float)s[0] + (float)s[1];
}

#define BARF() do { __builtin_amdgcn_s_barrier(); asm volatile("" ::: "memory"); } while (0)

// ==================== R4-style qkv: 128^2, 256 threads ====================

// async stage: 128x64 fp16 tile -> LDS, swizzled. 256 threads x 4 x 16B.
__device__ __forceinline__ void stage_async4(const _Float16* __restrict__ src, int ld,
                                             _Float16* __restrict__ dst, int wave, int lane) {
#pragma unroll
    for (int i = 0; i < 4; ++i) {
        int chunk = i * 4 + wave;
        int L = chunk * 64 + lane;
        int row = L >> 3, c8 = L & 7;
        int cg = c8 ^ (row & 7);
        __builtin_amdgcn_global_load_lds(
            (const __attribute__((address_space(1))) unsigned int*)(src + (size_t)row * ld + cg * 8),
            (__attribute__((address_space(3))) unsigned int*)(dst + chunk * 512),
            16, 0, 0);
    }
}

// one BK=64 K-step: swizzled ds_read_b128 frags + 16 MFMAs (4x4 16x16x32)
__device__ __forceinline__ void mfma_accum44(const _Float16* __restrict__ As,
                                             const _Float16* __restrict__ Bs,
                                             int wm, int wn, int l15, int q4,
                                             floatx4 acc[4][4]) {
#pragma unroll
    for (int kk = 0; kk < 2; ++kk) {
        half8 a[4], b[4];
#pragma unroll
        for (int i = 0; i < 4; ++i) {
            int row = wm * 64 + i * 16 + l15;
            int cg = (kk * 4 + q4) ^ (row & 7);
            a[i] = *(const half8*)(As + row * 64 + cg * 8);
        }
#pragma unroll
        for (int j = 0; j < 4; ++j) {
            int row = wn * 64 + j * 16 + l15;
            int cg = (kk * 4 + q4) ^ (row & 7);
            b[j] = *(const half8*)(Bs + row * 64 + cg * 8);
        }
#pragma unroll
        for (int i = 0; i < 4; ++i)
#pragma unroll
            for (int j = 0; j < 4; ++j)
                acc[i][j] = __builtin_amdgcn_mfma_f32_16x16x32_f16(a[i], b[j], acc[i][j], 0, 0, 0);
    }
}

// ================ R6-style gemm: 256^2, 512 threads, 4 phases ================

// async stage: one 128x64 half-tile (16 KB) -> LDS. 512 threads x 2 x 16B.
__device__ __forceinline__ void stage_ht(const _Float16* __restrict__ src, int ld,
                                         _Float16* __restrict__ dst, int wave, int lane) {
#pragma unroll
    for (int i = 0; i < 2; ++i) {
        int q = wave * 2 + i;            // 16 wave-chunks of 1 KB
        int c = q * 64 + lane;           // 8-elem chunk id in [0,1024)
        int row = c >> 3, c8 = c & 7;
        int cg = c8 ^ (row & 7);         // pre-swizzled global source colgroup
        __builtin_amdgcn_global_load_lds(
            (const __attribute__((address_space(1))) unsigned int*)(src + (size_t)row * ld + cg * 8),
            (__attribute__((address_space(3))) unsigned int*)(dst + q * 512),
            16, 0, 0);
    }
}

#define SA_(T, h) stage_ht(A + (size_t)((h) * 128) * lda + (size_t)(T) * 64, lda, \
                           ShA + (((T) & 1) * 2 + (h)) * 8192, wave, lane)
#define SB_(T, h) stage_ht(B + (size_t)((h) * 128) * ldb + (size_t)(T) * 64, ldb, \
                           ShB + (((T) & 1) * 2 + (h)) * 8192, wave, lane)

// 4 B-fragments for one K-half (kk)
__device__ __forceinline__ void read_b(const _Float16* __restrict__ Bs, int rb,
                                       int l15, int q4, int kk, half8 (&bf)[4]) {
#pragma unroll
    for (int j = 0; j < 4; ++j) {
        int rr = rb + j * 16 + l15;
        int cg = (kk * 4 + q4) ^ (rr & 7);
        bf[j] = *(const half8*)(Bs + rr * 64 + cg * 8);
    }
}

// 4 A-fragments (rows i0..i0+3) for one K-half (kk), optional rowsum
template<bool RSUM>
__device__ __forceinline__ void read_a(const _Float16* __restrict__ As, int i0,
                                       int l15, int q4, int kk, half8 (&af)[4],
                                       float* rsum) {
#pragma unroll
    for (int ii = 0; ii < 4; ++ii) {
        int rr = (i0 + ii) * 16 + l15;
        int cg = (kk * 4 + q4) ^ (rr & 7);
        af[ii] = *(const half8*)(As + rr * 64 + cg * 8);
        if (RSUM) rsum[i0 + ii] += sum8h(af[ii]);
    }
}

// lgkm0-aligned 16-MFMA cluster at prio 1
__device__ __forceinline__ void mfma16(const half8 (&af)[4], const half8 (&bf)[4],
                                       int i0, floatx4 (&acc)[8][4]) {
    asm volatile("s_waitcnt lgkmcnt(0)" ::: "memory");
    __builtin_amdgcn_sched_barrier(0);
    __builtin_amdgcn_s_setprio(1);
#pragma unroll
    for (int ii = 0; ii < 4; ++ii)
#pragma unroll
        for (int j = 0; j < 4; ++j)
            acc[i0 + ii][j] = __builtin_amdgcn_mfma_f32_16x16x32_f16(
                af[ii], bf[j], acc[i0 + ii][j], 0, 0, 0);
    __builtin_amdgcn_s_setprio(0);
}

// shared 256x256-tile GEMM main loop (4 uniform phases per K-tile)
template<bool RSUM>
__device__ __forceinline__ void gemm8p(const _Float16* __restrict__ A, int lda,
                                       const _Float16* __restrict__ B, int ldb,
                                       int K, _Float16* __restrict__ ShA,
                                       _Float16* __restrict__ ShB,
                                       int wave, int lane,
                                       floatx4 (&acc)[8][4], float (&rsum)[8]) {
    const int wm = wave >> 2, wn = wave & 3;
    const int l15 = lane & 15, q4 = lane >> 4;
    const int NT = K >> 6;

    // prologue: tile 0 fully + B(1); force tile 0, leave B(1) in flight
    SB_(0, 0); SB_(0, 1); SA_(0, 0); SA_(0, 1);
    SB_(1, 0); SB_(1, 1);
    asm volatile("s_waitcnt vmcnt(4)" ::: "memory");
    BARF();

    for (int t = 0; t < NT; ++t) {
        const _Float16* As = ShA + (t & 1) * 16384 + wm * 8192;
        const _Float16* Bs = ShB + (t & 1) * 16384 + (wn >> 1) * 8192;
        const int rb = (wn & 1) * 64;
        half8 bf[4], af[4];

        // ---- phase 0: reads {B kk0, A i0-3 kk0}, stage A0(t+1) ----
        read_b(Bs, rb, l15, q4, 0, bf);
        read_a<RSUM>(As, 0, l15, q4, 0, af, rsum);
        if (t + 1 < NT) SA_(t + 1, 0);
        BARF();
        mfma16(af, bf, 0, acc);
        BARF();

        // ---- phase 1: reads {A i4-7 kk0}, stage A1(t+1) ----
        read_a<RSUM>(As, 4, l15, q4, 0, af, rsum);
        if (t + 1 < NT) SA_(t + 1, 1);
        BARF();
        mfma16(af, bf, 4, acc);
        BARF();

        // ---- phase 2: reads {B kk1, A i0-3 kk1} ----
        read_b(Bs, rb, l15, q4, 1, bf);
        read_a<RSUM>(As, 0, l15, q4, 1, af, rsum);
        BARF();
        mfma16(af, bf, 0, acc);
        BARF();

        // ---- phase 3: reads {A i4-7 kk1}, stage B0/B1(t+2), vmcnt, publish ----
        read_a<RSUM>(As, 4, l15, q4, 1, af, rsum);
        if (t + 2 < NT) { SB_(t + 2, 0); SB_(t + 2, 1); }
        BARF();
        mfma16(af, bf, 4, acc);
        if (t + 1 < NT) {
            if (t + 2 < NT) asm volatile("s_waitcnt vmcnt(4)" ::: "memory");
            else            asm volatile("s_waitcnt vmcnt(0)" ::: "memory");
        }
        BARF();   // publishes tile t+1 for (t+1, phase 0)'s pre-bar reads
    }
}

// ============================ small kernels ============================

__global__ void cast_x(const float* __restrict__ X, _Float16* __restrict__ Xh) {
    size_t i = ((size_t)blockIdx.x * 256 + threadIdx.x) * 8;
    float4 v0 = *(const float4*)(X + i);
    float4 v1 = *(const float4*)(X + i + 4);
    half8 hh;
    hh[0] = (_Float16)v0.x; hh[1] = (_Float16)v0.y; hh[2] = (_Float16)v0.z; hh[3] = (_Float16)v0.w;
    hh[4] = (_Float16)v1.x; hh[5] = (_Float16)v1.y; hh[6] = (_Float16)v1.z; hh[7] = (_Float16)v1.w;
    *(half8*)(Xh + i) = hh;
}

__global__ void prep_weights(const float* __restrict__ Wq, const float* __restrict__ Wk,
                             const float* __restrict__ Wv, _Float16* __restrict__ WbT) {
    int g = blockIdx.z;
    const float* W = (g == 0) ? Wq : (g == 1) ? Wk : Wv;
    __shared__ float tile[32][33];
    int u0 = blockIdx.x * 32, d0 = blockIdx.y * 32;
    int tx = threadIdx.x & 31, ty = threadIdx.x >> 5;
#pragma unroll
    for (int i = 0; i < 32; i += 8)
        tile[ty + i][tx] = W[(size_t)(d0 + ty + i) * 1024 + (u0 + tx)];
    __syncthreads();
#pragma unroll
    for (int i = 0; i < 32; i += 8)
        WbT[(size_t)g * 1024 * 1024 + (size_t)(u0 + ty + i) * 1024 + (d0 + tx)] =
            (_Float16)tile[tx][ty + i];
}

// ---- kernel 2: fused QKV projection (R4 structure, 128^2, 256 threads) ----
// grid (24,128): blockIdx.x>>3 selects Q/K/V (block-uniform), &7 is the u-tile.
__global__ void qkv_gemm(const _Float16* __restrict__ Xh, const _Float16* __restrict__ WbT,
                         _Float16* __restrict__ Qh, _Float16* __restrict__ Kh,
                         _Float16* __restrict__ Vt) {
    __shared__ __align__(16) _Float16 As[128 * 64];
    __shared__ __align__(16) _Float16 Bs[128 * 64];
    int t = threadIdx.x;
    int lane = t & 63, wave = t >> 6;
    int wm = wave >> 1, wn = wave & 1;
    int l15 = lane & 15, q4 = lane >> 4;
    int m0 = blockIdx.y * 128, n0 = blockIdx.x * 128;
    floatx4 acc[4][4] = {};
    for (int kt = 0; kt < 1024; kt += 64) {
        __syncthreads();
        stage_async4(Xh + (size_t)m0 * 1024 + kt, 1024, As, wave, lane);
        stage_async4(WbT + (size_t)n0 * 1024 + kt, 1024, Bs, wave, lane);
        __syncthreads();
        mfma_accum44(As, Bs, wm, wn, l15, q4, acc);
    }
    // block-uniform routing: which matrix, which batch
    int which = blockIdx.x >> 3;            // 0=Q 1=K 2=V
    int u0 = (blockIdx.x & 7) * 128;        // column offset within 1024
    int b = m0 >> 11;                       // batch (128-row tiles never straddle)
    int sbase = (m0 & 2047) + wm * 64;      // sequence offset of this wave's rows
    if (which < 2) {
        _Float16* dst = which ? Kh : Qh;
        _Float16* db = dst + (size_t)b * 2048 * 1024;
#pragma unroll
        for (int i = 0; i < 4; ++i)
#pragma unroll
            for (int j = 0; j < 4; ++j)
#pragma unroll
                for (int r = 0; r < 4; ++r) {
                    int s = sbase + i * 16 + q4 * 4 + r;
                    int u = u0 + wn * 64 + j * 16 + l15;
                    db[(size_t)s * 1024 + u] = (_Float16)acc[i][j][r];
                }
    } else {
        _Float16* vb = Vt + (size_t)b * 1024 * 2048;
#pragma unroll
        for (int i = 0; i < 4; ++i)
#pragma unroll
            for (int j = 0; j < 4; ++j) {
                int s = sbase + i * 16 + q4 * 4;          // 4 consecutive s (r=0..3)
                int u = u0 + wn * 64 + j * 16 + l15;
                half4v pk;
#pragma unroll
                for (int r = 0; r < 4; ++r) pk[r] = (_Float16)acc[i][j][r];
                *(half4v*)(vb + (size_t)u * 2048 + s) = pk;  // 8B aligned (s%4==0)
            }
    }
}

// ---- kernel 3: scores (R6 structure, 256^2), epilogue = exp + store ----
__global__ __launch_bounds__(512, 2)
void scores_gemm(const _Float16* __restrict__ Qh, const _Float16* __restrict__ Kh,
                 _Float16* __restrict__ P) {
    __shared__ __align__(16) _Float16 ShA[32768];
    __shared__ __align__(16) _Float16 ShB[32768];
    int t = threadIdx.x;
    int lane = t & 63, wave = t >> 6;
    int wm = wave >> 2, wn = wave & 3;
    int l15 = lane & 15, q4 = lane >> 4;
    int m0 = blockIdx.y * 256, n0 = blockIdx.x * 256;
    int batch = blockIdx.z;
    const _Float16* A = Qh + (size_t)batch * 2048 * 1024 + (size_t)m0 * 1024;
    const _Float16* B = Kh + (size_t)batch * 2048 * 1024 + (size_t)n0 * 1024;
    floatx4 acc[8][4] = {};
    float rsum[8] = {};
    gemm8p<false>(A, 1024, B, 1024, 1024, ShA, ShB, wave, lane, acc, rsum);

    _Float16* Pb = P + (size_t)batch * 2048 * 2048;
#pragma unroll
    for (int i = 0; i < 8; ++i)
#pragma unroll
        for (int j = 0; j < 4; ++j)
#pragma unroll
            for (int r = 0; r < 4; ++r) {
                int m = m0 + wm * 128 + i * 16 + q4 * 4 + r;
                int n = n0 + wn * 64 + j * 16 + l15;
                Pb[(size_t)m * 2048 + n] = (_Float16)__expf(acc[i][j][r] * 0.03125f);
            }
}

// ---- kernel 4: P @ V (R6 structure, 256^2) with inline rowsum + norm ----
__global__ __launch_bounds__(512, 2)
void pv_gemm(const _Float16* __restrict__ P, const _Float16* __restrict__ Vt,
             float* __restrict__ out) {
    __shared__ __align__(16) _Float16 ShA[32768];
    __shared__ __align__(16) _Float16 ShB[32768];
    int t = threadIdx.x;
    int lane = t & 63, wave = t >> 6;
    int wm = wave >> 2, wn = wave & 3;
    int l15 = lane & 15, q4 = lane >> 4;
    int m0 = blockIdx.y * 256, n0 = blockIdx.x * 256;
    int batch = blockIdx.z;
    const _Float16* A = P + (size_t)batch * 2048 * 2048 + (size_t)m0 * 2048;
    const _Float16* B = Vt + (size_t)batch * 1024 * 2048 + (size_t)n0 * 2048;
    floatx4 acc[8][4] = {};
    float rsum[8] = {};
    gemm8p<true>(A, 2048, B, 2048, 2048, ShA, ShB, wave, lane, acc, rsum);

    // merge the 4 q4 k-slices: lanes sharing l15 hold partials of the same row
    float rsumf[8];
#pragma unroll
    for (int i = 0; i < 8; ++i) {
        float v = rsum[i] + __shfl_xor(rsum[i], 16);
        rsumf[i] = v + __shfl_xor(v, 32);   // full rowsum of row i*16+l15
    }
    float* ob = out + (size_t)batch * 2048 * 1024;
#pragma unroll
    for (int i = 0; i < 8; ++i)
#pragma unroll
        for (int r = 0; r < 4; ++r) {
            int rloc = q4 * 4 + r;                       // C/D row within 16x16
            float inv = 1.0f / __shfl(rsumf[i], rloc);   // lane rloc holds it
            int m = m0 + wm * 128 + i * 16 + rloc;
#pragma unroll
            for (int j = 0; j < 4; ++j) {
                int n = n0 + wn * 64 + j * 16 + l15;
                ob[(size_t)m * 1024 + n] = acc[i][j][r] * inv;
            }
        }
}

extern "C" void kernel_launch(void* const* d_in, const int* in_sizes, int n_in,
                              void* d_out, int out_size, void* d_ws, size_t ws_size,
                              hipStream_t stream) {
    const float* X  = (const float*)d_in[0];
    const float* Wq = (const float*)d_in[1];
    const float* Wk = (const float*)d_in[2];
    const float* Wv = (const float*)d_in[3];
    float* out = (float*)d_out;

    char* ws = (char*)d_ws;
    size_t off = 0;
    _Float16* Xh  = (_Float16*)(ws + off); off += (size_t)8 * 2048 * 1024 * 2;
    _Float16* WbT = (_Float16*)(ws + off); off += (size_t)3 * 1024 * 1024 * 2;
    _Float16* Qh  = (_Float16*)(ws + off); off += (size_t)8 * 2048 * 1024 * 2;
    _Float16* Kh  = (_Float16*)(ws + off); off += (size_t)8 * 2048 * 1024 * 2;
    _Float16* Vt  = (_Float16*)(ws + off); off += (size_t)8 * 1024 * 2048 * 2;
    _Float16* P   = (_Float16*)(ws + off); off += (size_t)8 * 2048 * 2048 * 2;

    cast_x      <<<dim3(8192, 1, 1), 256, 0, stream>>>(X, Xh);
    prep_weights<<<dim3(32, 32, 3), 256, 0, stream>>>(Wq, Wk, Wv, WbT);
    qkv_gemm    <<<dim3(24, 128, 1), 256, 0, stream>>>(Xh, WbT, Qh, Kh, Vt);
    scores_gemm <<<dim3(8, 8, 8),   512, 0, stream>>>(Qh, Kh, P);
    pv_gemm     <<<dim3(4, 8, 8),   512, 0, stream>>>(P, Vt, out);
}

// Round 7
// 373.644 us; speedup vs baseline: 1.1312x; 1.0690x over previous
//
#include <hip/hip_runtime.h>

// SelfAttention: B=8, S=2048, D=1024, U=1024, fp32 in/out.
// R11 = R10 resubmitted verbatim (R10 bench failed on container acquisition,
// no GPU data produced; source is a pure index-permutation delta vs R9).
// R10 = R9 + XCD-aware chunked block swizzle (T1) on all three GEMMs.
// Diagnosis: scores/pv run at ~half qkv's per-FLOP rate in every schedule
// tried (R4-R9). qkv's operands (WbT 6.3MB, hot A-slab) are L2-resident;
// scores/pv stage from 33-67MB working sets -> with default round-robin
// block->XCD dispatch each XCD's 4MB L2 thrashes and staging runs at
// LLC/HBM latency, inflating every per-tile sync stall.
// Swizzle (w = (lin%8)*(T/8) + lin/8, all grids %8==0 -> bijective):
//  - scores (8,8,8):  one batch per XCD; K_batch 4MB fits L2; Q-slab hot
//    across 8 consecutive n-blocks.
//  - pv     (4,8,8):  one batch per XCD; V_batch 4MB fits L2; P-slab shared
//    by 4 consecutive u-blocks.
//  - qkv    (24,128): chunk = 16 m-slabs x all 24 (which,u)-tiles; A-slab
//    hot across 24 consecutive blocks, WbT mostly L2.
// Kernel structures unchanged from R9 (qkv: R4-style 128^2/2-phase/256t;
// scores/pv: R6-style 256^2/4-phase/512t). Staging swizzle everywhere:
// LDS slot (row,c8) holds global colgroup c8^(row&7), conflict-free.
// Workspace: 33.6(Xh) + 6.3(WbT) + 33.6*3(QKV) + 67.1(P) = 207.7 MB

typedef _Float16 half8  __attribute__((ext_vector_type(8)));
typedef _Float16 half4v __attribute__((ext_vector_type(4)));
typedef _Float16 half2v __attribute__((ext_vector_type(2)));
typedef float    floatx4 __attribute__((ext_vector_type(4)));

// ============================ shared helpers ============================

// pk-add sum of 8 halves -> float
__device__ __forceinline__ float sum8h(half8 a) {
    union { half8 v; half2v h2[4]; } u; u.v = a;
    half2v s0 = u.h2[0] + u.h2[1];
    half2v s1 = u.h2[2] + u.h2[3];
    half2v s  = s0 + s1;
    return (float)s[0] + (float)s[1];
}

#define BARF() do { __builtin_amdgcn_s_barrier(); asm volatile("" ::: "memory"); } while (0)

// XCD-chunked work-id: dispatch-order lin -> contiguous chunk per XCD.
// TOT must be divisible by 8 (all our grids are).
template<int TOT>
__device__ __forceinline__ int xcd_swz(int lin) {
    return (lin & 7) * (TOT >> 3) + (lin >> 3);
}

// ==================== R4-style qkv: 128^2, 256 threads ====================

// async stage: 128x64 fp16 tile -> LDS, swizzled. 256 threads x 4 x 16B.
__device__ __forceinline__ void stage_async4(const _Float16* __restrict__ src, int ld,
                                             _Float16* __restrict__ dst, int wave, int lane) {
#pragma unroll
    for (int i = 0; i < 4; ++i) {
        int chunk = i * 4 + wave;
        int L = chunk * 64 + lane;
        int row = L >> 3, c8 = L & 7;
        int cg = c8 ^ (row & 7);
        __builtin_amdgcn_global_load_lds(
            (const __attribute__((address_space(1))) unsigned int*)(src + (size_t)row * ld + cg * 8),
            (__attribute__((address_space(3))) unsigned int*)(dst + chunk * 512),
            16, 0, 0);
    }
}

// one BK=64 K-step: swizzled ds_read_b128 frags + 16 MFMAs (4x4 16x16x32)
__device__ __forceinline__ void mfma_accum44(const _Float16* __restrict__ As,
                                             const _Float16* __restrict__ Bs,
                                             int wm, int wn, int l15, int q4,
                                             floatx4 acc[4][4]) {
#pragma unroll
    for (int kk = 0; kk < 2; ++kk) {
        half8 a[4], b[4];
#pragma unroll
        for (int i = 0; i < 4; ++i) {
            int row = wm * 64 + i * 16 + l15;
            int cg = (kk * 4 + q4) ^ (row & 7);
            a[i] = *(const half8*)(As + row * 64 + cg * 8);
        }
#pragma unroll
        for (int j = 0; j < 4; ++j) {
            int row = wn * 64 + j * 16 + l15;
            int cg = (kk * 4 + q4) ^ (row & 7);
            b[j] = *(const half8*)(Bs + row * 64 + cg * 8);
        }
#pragma unroll
        for (int i = 0; i < 4; ++i)
#pragma unroll
            for (int j = 0; j < 4; ++j)
                acc[i][j] = __builtin_amdgcn_mfma_f32_16x16x32_f16(a[i], b[j], acc[i][j], 0, 0, 0);
    }
}

// ================ R6-style gemm: 256^2, 512 threads, 4 phases ================

// async stage: one 128x64 half-tile (16 KB) -> LDS. 512 threads x 2 x 16B.
__device__ __forceinline__ void stage_ht(const _Float16* __restrict__ src, int ld,
                                         _Float16* __restrict__ dst, int wave, int lane) {
#pragma unroll
    for (int i = 0; i < 2; ++i) {
        int q = wave * 2 + i;            // 16 wave-chunks of 1 KB
        int c = q * 64 + lane;           // 8-elem chunk id in [0,1024)
        int row = c >> 3, c8 = c & 7;
        int cg = c8 ^ (row & 7);         // pre-swizzled global source colgroup
        __builtin_amdgcn_global_load_lds(
            (const __attribute__((address_space(1))) unsigned int*)(src + (size_t)row * ld + cg * 8),
            (__attribute__((address_space(3))) unsigned int*)(dst + q * 512),
            16, 0, 0);
    }
}

#define SA_(T, h) stage_ht(A + (size_t)((h) * 128) * lda + (size_t)(T) * 64, lda, \
                           ShA + (((T) & 1) * 2 + (h)) * 8192, wave, lane)
#define SB_(T, h) stage_ht(B + (size_t)((h) * 128) * ldb + (size_t)(T) * 64, ldb, \
                           ShB + (((T) & 1) * 2 + (h)) * 8192, wave, lane)

// 4 B-fragments for one K-half (kk)
__device__ __forceinline__ void read_b(const _Float16* __restrict__ Bs, int rb,
                                       int l15, int q4, int kk, half8 (&bf)[4]) {
#pragma unroll
    for (int j = 0; j < 4; ++j) {
        int rr = rb + j * 16 + l15;
        int cg = (kk * 4 + q4) ^ (rr & 7);
        bf[j] = *(const half8*)(Bs + rr * 64 + cg * 8);
    }
}

// 4 A-fragments (rows i0..i0+3) for one K-half (kk), optional rowsum
template<bool RSUM>
__device__ __forceinline__ void read_a(const _Float16* __restrict__ As, int i0,
                                       int l15, int q4, int kk, half8 (&af)[4],
                                       float* rsum) {
#pragma unroll
    for (int ii = 0; ii < 4; ++ii) {
        int rr = (i0 + ii) * 16 + l15;
        int cg = (kk * 4 + q4) ^ (rr & 7);
        af[ii] = *(const half8*)(As + rr * 64 + cg * 8);
        if (RSUM) rsum[i0 + ii] += sum8h(af[ii]);
    }
}

// lgkm0-aligned 16-MFMA cluster at prio 1
__device__ __forceinline__ void mfma16(const half8 (&af)[4], const half8 (&bf)[4],
                                       int i0, floatx4 (&acc)[8][4]) {
    asm volatile("s_waitcnt lgkmcnt(0)" ::: "memory");
    __builtin_amdgcn_sched_barrier(0);
    __builtin_amdgcn_s_setprio(1);
#pragma unroll
    for (int ii = 0; ii < 4; ++ii)
#pragma unroll
        for (int j = 0; j < 4; ++j)
            acc[i0 + ii][j] = __builtin_amdgcn_mfma_f32_16x16x32_f16(
                af[ii], bf[j], acc[i0 + ii][j], 0, 0, 0);
    __builtin_amdgcn_s_setprio(0);
}

// shared 256x256-tile GEMM main loop (4 uniform phases per K-tile)
template<bool RSUM>
__device__ __forceinline__ void gemm8p(const _Float16* __restrict__ A, int lda,
                                       const _Float16* __restrict__ B, int ldb,
                                       int K, _Float16* __restrict__ ShA,
                                       _Float16* __restrict__ ShB,
                                       int wave, int lane,
                                       floatx4 (&acc)[8][4], float (&rsum)[8]) {
    const int wm = wave >> 2, wn = wave & 3;
    const int l15 = lane & 15, q4 = lane >> 4;
    const int NT = K >> 6;

    // prologue: tile 0 fully + B(1); force tile 0, leave B(1) in flight
    SB_(0, 0); SB_(0, 1); SA_(0, 0); SA_(0, 1);
    SB_(1, 0); SB_(1, 1);
    asm volatile("s_waitcnt vmcnt(4)" ::: "memory");
    BARF();

    for (int t = 0; t < NT; ++t) {
        const _Float16* As = ShA + (t & 1) * 16384 + wm * 8192;
        const _Float16* Bs = ShB + (t & 1) * 16384 + (wn >> 1) * 8192;
        const int rb = (wn & 1) * 64;
        half8 bf[4], af[4];

        // ---- phase 0: reads {B kk0, A i0-3 kk0}, stage A0(t+1) ----
        read_b(Bs, rb, l15, q4, 0, bf);
        read_a<RSUM>(As, 0, l15, q4, 0, af, rsum);
        if (t + 1 < NT) SA_(t + 1, 0);
        BARF();
        mfma16(af, bf, 0, acc);
        BARF();

        // ---- phase 1: reads {A i4-7 kk0}, stage A1(t+1) ----
        read_a<RSUM>(As, 4, l15, q4, 0, af, rsum);
        if (t + 1 < NT) SA_(t + 1, 1);
        BARF();
        mfma16(af, bf, 4, acc);
        BARF();

        // ---- phase 2: reads {B kk1, A i0-3 kk1} ----
        read_b(Bs, rb, l15, q4, 1, bf);
        read_a<RSUM>(As, 0, l15, q4, 1, af, rsum);
        BARF();
        mfma16(af, bf, 0, acc);
        BARF();

        // ---- phase 3: reads {A i4-7 kk1}, stage B0/B1(t+2), vmcnt, publish ----
        read_a<RSUM>(As, 4, l15, q4, 1, af, rsum);
        if (t + 2 < NT) { SB_(t + 2, 0); SB_(t + 2, 1); }
        BARF();
        mfma16(af, bf, 4, acc);
        if (t + 1 < NT) {
            if (t + 2 < NT) asm volatile("s_waitcnt vmcnt(4)" ::: "memory");
            else            asm volatile("s_waitcnt vmcnt(0)" ::: "memory");
        }
        BARF();   // publishes tile t+1 for (t+1, phase 0)'s pre-bar reads
    }
}

// ============================ small kernels ============================

__global__ void cast_x(const float* __restrict__ X, _Float16* __restrict__ Xh) {
    size_t i = ((size_t)blockIdx.x * 256 + threadIdx.x) * 8;
    float4 v0 = *(const float4*)(X + i);
    float4 v1 = *(const float4*)(X + i + 4);
    half8 hh;
    hh[0] = (_Float16)v0.x; hh[1] = (_Float16)v0.y; hh[2] = (_Float16)v0.z; hh[3] = (_Float16)v0.w;
    hh[4] = (_Float16)v1.x; hh[5] = (_Float16)v1.y; hh[6] = (_Float16)v1.z; hh[7] = (_Float16)v1.w;
    *(half8*)(Xh + i) = hh;
}

__global__ void prep_weights(const float* __restrict__ Wq, const float* __restrict__ Wk,
                             const float* __restrict__ Wv, _Float16* __restrict__ WbT) {
    int g = blockIdx.z;
    const float* W = (g == 0) ? Wq : (g == 1) ? Wk : Wv;
    __shared__ float tile[32][33];
    int u0 = blockIdx.x * 32, d0 = blockIdx.y * 32;
    int tx = threadIdx.x & 31, ty = threadIdx.x >> 5;
#pragma unroll
    for (int i = 0; i < 32; i += 8)
        tile[ty + i][tx] = W[(size_t)(d0 + ty + i) * 1024 + (u0 + tx)];
    __syncthreads();
#pragma unroll
    for (int i = 0; i < 32; i += 8)
        WbT[(size_t)g * 1024 * 1024 + (size_t)(u0 + ty + i) * 1024 + (d0 + tx)] =
            (_Float16)tile[tx][ty + i];
}

// ---- kernel 2: fused QKV projection (R4 structure, 128^2, 256 threads) ----
// grid (24,128); XCD-swizzled: chunk = 16 m-slabs x all 24 (which,u)-tiles.
__global__ void qkv_gemm(const _Float16* __restrict__ Xh, const _Float16* __restrict__ WbT,
                         _Float16* __restrict__ Qh, _Float16* __restrict__ Kh,
                         _Float16* __restrict__ Vt) {
    __shared__ __align__(16) _Float16 As[128 * 64];
    __shared__ __align__(16) _Float16 Bs[128 * 64];
    int t = threadIdx.x;
    int lane = t & 63, wave = t >> 6;
    int wm = wave >> 1, wn = wave & 1;
    int l15 = lane & 15, q4 = lane >> 4;
    int w = xcd_swz<24 * 128>(blockIdx.x + 24 * blockIdx.y);
    int bx = w % 24, by = w / 24;
    int m0 = by * 128, n0 = bx * 128;
    floatx4 acc[4][4] = {};
    for (int kt = 0; kt < 1024; kt += 64) {
        __syncthreads();
        stage_async4(Xh + (size_t)m0 * 1024 + kt, 1024, As, wave, lane);
        stage_async4(WbT + (size_t)n0 * 1024 + kt, 1024, Bs, wave, lane);
        __syncthreads();
        mfma_accum44(As, Bs, wm, wn, l15, q4, acc);
    }
    // block-uniform routing: which matrix, which batch
    int which = bx >> 3;                    // 0=Q 1=K 2=V
    int u0 = (bx & 7) * 128;                // column offset within 1024
    int b = m0 >> 11;                       // batch (128-row tiles never straddle)
    int sbase = (m0 & 2047) + wm * 64;      // sequence offset of this wave's rows
    if (which < 2) {
        _Float16* dst = which ? Kh : Qh;
        _Float16* db = dst + (size_t)b * 2048 * 1024;
#pragma unroll
        for (int i = 0; i < 4; ++i)
#pragma unroll
            for (int j = 0; j < 4; ++j)
#pragma unroll
                for (int r = 0; r < 4; ++r) {
                    int s = sbase + i * 16 + q4 * 4 + r;
                    int u = u0 + wn * 64 + j * 16 + l15;
                    db[(size_t)s * 1024 + u] = (_Float16)acc[i][j][r];
                }
    } else {
        _Float16* vb = Vt + (size_t)b * 1024 * 2048;
#pragma unroll
        for (int i = 0; i < 4; ++i)
#pragma unroll
            for (int j = 0; j < 4; ++j) {
                int s = sbase + i * 16 + q4 * 4;          // 4 consecutive s (r=0..3)
                int u = u0 + wn * 64 + j * 16 + l15;
                half4v pk;
#pragma unroll
                for (int r = 0; r < 4; ++r) pk[r] = (_Float16)acc[i][j][r];
                *(half4v*)(vb + (size_t)u * 2048 + s) = pk;  // 8B aligned (s%4==0)
            }
    }
}

// ---- kernel 3: scores (R6 structure, 256^2), epilogue = exp + store ----
// grid (8,8,8); XCD-swizzled: one batch per XCD (K_batch 4MB fits L2).
__global__ __launch_bounds__(512, 2)
void scores_gemm(const _Float16* __restrict__ Qh, const _Float16* __restrict__ Kh,
                 _Float16* __restrict__ P) {
    __shared__ __align__(16) _Float16 ShA[32768];
    __shared__ __align__(16) _Float16 ShB[32768];
    int t = threadIdx.x;
    int lane = t & 63, wave = t >> 6;
    int wm = wave >> 2, wn = wave & 3;
    int l15 = lane & 15, q4 = lane >> 4;
    int w = xcd_swz<8 * 8 * 8>(blockIdx.x + 8 * (blockIdx.y + 8 * blockIdx.z));
    int bx = w & 7, by = (w >> 3) & 7, batch = w >> 6;
    int m0 = by * 256, n0 = bx * 256;
    const _Float16* A = Qh + (size_t)batch * 2048 * 1024 + (size_t)m0 * 1024;
    const _Float16* B = Kh + (size_t)batch * 2048 * 1024 + (size_t)n0 * 1024;
    floatx4 acc[8][4] = {};
    float rsum[8] = {};
    gemm8p<false>(A, 1024, B, 1024, 1024, ShA, ShB, wave, lane, acc, rsum);

    _Float16* Pb = P + (size_t)batch * 2048 * 2048;
#pragma unroll
    for (int i = 0; i < 8; ++i)
#pragma unroll
        for (int j = 0; j < 4; ++j)
#pragma unroll
            for (int r = 0; r < 4; ++r) {
                int m = m0 + wm * 128 + i * 16 + q4 * 4 + r;
                int n = n0 + wn * 64 + j * 16 + l15;
                Pb[(size_t)m * 2048 + n] = (_Float16)__expf(acc[i][j][r] * 0.03125f);
            }
}

// ---- kernel 4: P @ V (R6 structure, 256^2) with inline rowsum + norm ----
// grid (4,8,8); XCD-swizzled: one batch per XCD (V_batch 4MB fits L2).
__global__ __launch_bounds__(512, 2)
void pv_gemm(const _Float16* __restrict__ P, const _Float16* __restrict__ Vt,
             float* __restrict__ out) {
    __shared__ __align__(16) _Float16 ShA[32768];
    __shared__ __align__(16) _Float16 ShB[32768];
    int t = threadIdx.x;
    int lane = t & 63, wave = t >> 6;
    int wm = wave >> 2, wn = wave & 3;
    int l15 = lane & 15, q4 = lane >> 4;
    int w = xcd_swz<4 * 8 * 8>(blockIdx.x + 4 * (blockIdx.y + 8 * blockIdx.z));
    int bx = w & 3, by = (w >> 2) & 7, batch = w >> 5;
    int m0 = by * 256, n0 = bx * 256;
    const _Float16* A = P + (size_t)batch * 2048 * 2048 + (size_t)m0 * 2048;
    const _Float16* B = Vt + (size_t)batch * 1024 * 2048 + (size_t)n0 * 2048;
    floatx4 acc[8][4] = {};
    float rsum[8] = {};
    gemm8p<true>(A, 2048, B, 2048, 2048, ShA, ShB, wave, lane, acc, rsum);

    // merge the 4 q4 k-slices: lanes sharing l15 hold partials of the same row
    float rsumf[8];
#pragma unroll
    for (int i = 0; i < 8; ++i) {
        float v = rsum[i] + __shfl_xor(rsum[i], 16);
        rsumf[i] = v + __shfl_xor(v, 32);   // full rowsum of row i*16+l15
    }
    float* ob = out + (size_t)batch * 2048 * 1024;
#pragma unroll
    for (int i = 0; i < 8; ++i)
#pragma unroll
        for (int r = 0; r < 4; ++r) {
            int rloc = q4 * 4 + r;                       // C/D row within 16x16
            float inv = 1.0f / __shfl(rsumf[i], rloc);   // lane rloc holds it
            int m = m0 + wm * 128 + i * 16 + rloc;
#pragma unroll
            for (int j = 0; j < 4; ++j) {
                int n = n0 + wn * 64 + j * 16 + l15;
                ob[(size_t)m * 1024 + n] = acc[i][j][r] * inv;
            }
        }
}

extern "C" void kernel_launch(void* const* d_in, const int* in_sizes, int n_in,
                              void* d_out, int out_size, void* d_ws, size_t ws_size,
                              hipStream_t stream) {
    const float* X  = (const float*)d_in[0];
    const float* Wq = (const float*)d_in[1];
    const float* Wk = (const float*)d_in[2];
    const float* Wv = (const float*)d_in[3];
    float* out = (float*)d_out;

    char* ws = (char*)d_ws;
    size_t off = 0;
    _Float16* Xh  = (_Float16*)(ws + off); off += (size_t)8 * 2048 * 1024 * 2;
    _Float16* WbT = (_Float16*)(ws + off); off += (size_t)3 * 1024 * 1024 * 2;
    _Float16* Qh  = (_Float16*)(ws + off); off += (size_t)8 * 2048 * 1024 * 2;
    _Float16* Kh  = (_Float16*)(ws + off); off += (size_t)8 * 2048 * 1024 * 2;
    _Float16* Vt  = (_Float16*)(ws + off); off += (size_t)8 * 1024 * 2048 * 2;
    _Float16* P   = (_Float16*)(ws + off); off += (size_t)8 * 2048 * 2048 * 2;

    cast_x      <<<dim3(8192, 1, 1), 256, 0, stream>>>(X, Xh);
    prep_weights<<<dim3(32, 32, 3), 256, 0, stream>>>(Wq, Wk, Wv, WbT);
    qkv_gemm    <<<dim3(24, 128, 1), 256, 0, stream>>>(Xh, WbT, Qh, Kh, Vt);
    scores_gemm <<<dim3(8, 8, 8),   512, 0, stream>>>(Qh, Kh, P);
    pv_gemm     <<<dim3(4, 8, 8),   512, 0, stream>>>(P, Vt, out);
}